// Round 7
// baseline (228.009 us; speedup 1.0000x reference)
//
#include <hip/hip_runtime.h>

typedef __attribute__((ext_vector_type(8))) short bf16x8;
typedef __attribute__((ext_vector_type(4))) float f32x4;
typedef __attribute__((ext_vector_type(4))) unsigned short u16x4;
typedef __attribute__((ext_vector_type(8))) unsigned short u16x8;

#define B_ 2048
#define A_ 50
#define H_ 512
#define NACT_ 64
#define F_ 562

// ws layout (bytes)
#define WS_W1T 0
#define WS_W2T ((size_t)A_ * H_ * H_ * 2)                    /* 26,214,400 */
#define WS_B1 (WS_W2T + (size_t)A_ * NACT_ * H_ * 2)         /* 29,491,200 */
#define WS_B2 (WS_B1 + (size_t)A_ * H_ * 4)                  /* 29,593,600 */

static __device__ __forceinline__ unsigned short f2bf(float f) {
  unsigned int u = __builtin_bit_cast(unsigned int, f);
  u += 0x7fffu + ((u >> 16) & 1u);
  return (unsigned short)(u >> 16);
}

static __device__ __forceinline__ void gld_lds16(const unsigned short* src,
                                                 unsigned short* dst) {
  __builtin_amdgcn_global_load_lds(
      (const __attribute__((address_space(1))) unsigned int*)(const void*)src,
      (__attribute__((address_space(3))) unsigned int*)(void*)dst, 16, 0, 0);
}

static __device__ __forceinline__ int clamp_r(int r) {
  return r < 0 ? 0 : (r > A_ - 1 ? A_ - 1 : r);
}

// W1T layout: [a][slab s=k>>5 (16)][j 512][pos 4][e 8]; 16B chunk at pos p
// holds logical within-slab chunk c = p ^ ((j>>1)&3). Slab = contiguous 32KB.
__global__ void prep_w1_n(const float* __restrict__ w1,
                          const int* __restrict__ routing,
                          unsigned short* __restrict__ w1t) {
  const int bid = blockIdx.x;
  const int a = bid / 64;
  const int tile = bid - a * 64;
  const int tk = tile & 7, tj = tile >> 3;
  const int k0 = tk * 64, j0 = tj * 64;
  const int r = clamp_r(routing[a]);
  __shared__ float tl[64][65];
  const int t = threadIdx.x;
  const int c = t & 63, q = t >> 6;
#pragma unroll
  for (int i = 0; i < 16; ++i) {
    const int kl = q + i * 4;
    tl[kl][c] = w1[((size_t)r * F_ + k0 + kl) * H_ + j0 + c];
  }
  __syncthreads();
  const int jl = t >> 2, pq = t & 3;
  const int sx = (jl >> 1) & 3;
#pragma unroll
  for (int it = 0; it < 2; ++it) {
    const int cc = pq ^ sx; // logical chunk held at position pq
    u16x8 v;
#pragma unroll
    for (int e = 0; e < 8; ++e) v[e] = f2bf(tl[it * 32 + cc * 8 + e][jl]);
    unsigned short* dst =
        w1t + (((size_t)a * 16 + tk * 2 + it) * H_ + j0 + jl) * 32 + pq * 8;
    *(u16x8*)dst = v;
  }
}

// W2T[a][n][k] = bf16(W2[r_a][k][n])  (plain, k-contiguous rows)
__global__ void prep_w2(const float* __restrict__ w2,
                        const int* __restrict__ routing,
                        unsigned short* __restrict__ w2t) {
  const int bid = blockIdx.x;
  const int a = bid >> 3;
  const int tk = bid & 7;
  const int k0 = tk * 64;
  const int r = clamp_r(routing[a]);
  __shared__ float tl[64][65];
  const int t = threadIdx.x;
  const int c = t & 63, q = t >> 6;
#pragma unroll
  for (int i = 0; i < 16; ++i) {
    const int kl = q + i * 4;
    tl[kl][c] = w2[((size_t)r * H_ + k0 + kl) * NACT_ + c];
  }
  __syncthreads();
#pragma unroll
  for (int i = 0; i < 16; ++i) {
    const int nl = q + i * 4;
    w2t[((size_t)a * NACT_ + nl) * H_ + k0 + c] = f2bf(tl[c][nl]);
  }
}

__global__ void prep_bias(const float* __restrict__ w1,
                          const float* __restrict__ b1,
                          const float* __restrict__ b2,
                          const int* __restrict__ routing,
                          float* __restrict__ bias1, float* __restrict__ bias2) {
  const int a = blockIdx.x;
  const int t = threadIdx.x;
  const int r = clamp_r(routing[a]);
  bias1[a * H_ + t] = b1[(size_t)r * H_ + t] + w1[((size_t)r * F_ + H_ + a) * H_ + t];
  if (t < NACT_) bias2[a * NACT_ + t] = b2[r * NACT_ + t];
}

// Fused main: x-tile staged ONCE (full contiguous rows -> channel-dense),
// W1 triple-buffered slab stream, K2 fused. LDS = 160 KiB.
__global__ __launch_bounds__(512, 2) void divtree_v7(
    const float* __restrict__ x, const unsigned short* __restrict__ w1t,
    const unsigned short* __restrict__ w2t, const float* __restrict__ bias1,
    const float* __restrict__ bias2, float* __restrict__ out) {
  __shared__ union {
    struct {
      unsigned short xs[64 * 512];    // 64 KiB, stationary x tile (swizzled)
      unsigned short w1[3][512 * 32]; // 96 KiB, slab triple-buffer
    } st;
    unsigned short h[64 * 512];       // aliases xs (after K-loop)
    struct {
      unsigned short pad[64 * 512];
      float outb[64][66];             // aliases w1 (after layer 2)
    } ep;
  } sm;

  // XCD-bijective swizzle: 1600 blocks, cpx = 200
  const int bid = blockIdx.x;
  const int swz = (bid & 7) * 200 + (bid >> 3);
  const int a = swz >> 5;    // 0..49
  const int mblk = swz & 31; // 0..31
  const int b0 = mblk * 64;

  const int tid = threadIdx.x;
  const int lane = tid & 63;
  const int w = tid >> 6; // wave 0..7
  const int l16 = lane & 15;
  const int lk = lane >> 4;
  const int l7 = l16 & 7;
  const int wj = w * 64; // wave j tile: 64 rows

  const unsigned short* w1ta = w1t + (size_t)a * (16 * H_ * 32);

  // prologue x mapping: row xm = tid>>3, 64-float segment xq = tid&7
  const int xm = tid >> 3;
  const int xq = tid & 7;
  const float* xrowp =
      x + ((size_t)(b0 + xm) * A_ + (size_t)a) * H_ + (size_t)xq * 64;

  const int afr_base = (wj + l16) * 32 + (lk ^ ((l16 >> 1) & 3)) * 8;

  f32x4 acc[4][4];
#pragma unroll
  for (int i = 0; i < 4; ++i)
#pragma unroll
    for (int j = 0; j < 4; ++j) acc[i][j] = (f32x4){0.f, 0.f, 0.f, 0.f};

  // ---- prologue: full-row x reads (contiguous 256B/thread), W1 slabs 0,1 ----
  {
    f32x4 xv[16];
#pragma unroll
    for (int i = 0; i < 16; ++i) xv[i] = *(const f32x4*)(xrowp + i * 4);
#pragma unroll
    for (int i = 0; i < 4; ++i)
      gld_lds16(w1ta + (size_t)(i * 512 + tid) * 8,
                sm.st.w1[0] + (i * 512 + tid) * 8);
#pragma unroll
    for (int i = 0; i < 4; ++i)
      gld_lds16(w1ta + 16384 + (size_t)(i * 512 + tid) * 8,
                sm.st.w1[1] + (i * 512 + tid) * 8);
    // cvt + swizzled xs writes: chunk c at pos c ^ (row&7)
#pragma unroll
    for (int j = 0; j < 8; ++j) {
      u16x8 v;
#pragma unroll
      for (int e = 0; e < 4; ++e) {
        v[e] = f2bf(xv[2 * j][e]);
        v[4 + e] = f2bf(xv[2 * j + 1][e]);
      }
      const int c = xq * 8 + j;
      *(u16x8*)(sm.st.xs + xm * 512 + (c ^ (xm & 7)) * 8) = v;
    }
    asm volatile("s_waitcnt vmcnt(4) lgkmcnt(0)" ::: "memory");
    __builtin_amdgcn_sched_barrier(0);
    __builtin_amdgcn_s_barrier();
    __builtin_amdgcn_sched_barrier(0);
  }

  // ---- K-loop: 16 steps, W1 triple-buffer, vmcnt(4) (2-step cover) ----
#pragma unroll
  for (int t = 0; t < 16; ++t) {
    const int buf = t % 3;
    if (t + 2 < 16) { // issue slab t+2 into w1[(t+2)%3] (read at t-1 done)
      const unsigned short* src = w1ta + (size_t)(t + 2) * 16384;
      unsigned short* dst = sm.st.w1[(t + 2) % 3];
#pragma unroll
      for (int i = 0; i < 4; ++i)
        gld_lds16(src + (size_t)(i * 512 + tid) * 8,
                  dst + (i * 512 + tid) * 8);
    }
    const unsigned short* w1s = sm.st.w1[buf];
    bf16x8 afr[4], bfr[4];
#pragma unroll
    for (int jf = 0; jf < 4; ++jf)
      afr[jf] = *(const bf16x8*)(w1s + afr_base + jf * 512);
    const int post = ((t * 4 + lk) ^ l7) * 8;
#pragma unroll
    for (int mf = 0; mf < 4; ++mf)
      bfr[mf] = *(const bf16x8*)(sm.st.xs + (mf * 16 + l16) * 512 + post);
    __builtin_amdgcn_s_setprio(1);
#pragma unroll
    for (int jf = 0; jf < 4; ++jf)
#pragma unroll
      for (int mf = 0; mf < 4; ++mf)
        acc[jf][mf] = __builtin_amdgcn_mfma_f32_16x16x32_bf16(
            afr[jf], bfr[mf], acc[jf][mf], 0, 0, 0);
    __builtin_amdgcn_s_setprio(0);
    if (t + 2 < 16)
      asm volatile("s_waitcnt vmcnt(4)" ::: "memory"); // slab t+1 landed
    else
      asm volatile("s_waitcnt vmcnt(0)" ::: "memory");
    __builtin_amdgcn_sched_barrier(0);
    __builtin_amdgcn_s_barrier();
    __builtin_amdgcn_sched_barrier(0);
  }

  // ---- h = relu(acc + bias1_eff) -> LDS (xs region), XOR-swizzled ----
  const float* b1p = bias1 + a * H_;
#pragma unroll
  for (int jf = 0; jf < 4; ++jf) {
    const f32x4 bv = *(const f32x4*)(b1p + wj + jf * 16 + lk * 4);
    const int cbase = (wj >> 3) + jf * 2 + (lk >> 1);
    const int half4 = (lk & 1) * 4;
#pragma unroll
    for (int mf = 0; mf < 4; ++mf) {
      u16x4 hv;
#pragma unroll
      for (int r = 0; r < 4; ++r) {
        float f = acc[jf][mf][r] + bv[r];
        f = f > 0.f ? f : 0.f;
        hv[r] = f2bf(f);
      }
      const int m = mf * 16 + l16;
      const int off = m * H_ + ((cbase ^ (l16 & 7))) * 8 + half4;
      *(u16x4*)(sm.h + off) = hv;
    }
  }
  __syncthreads();

  // ---- layer 2: wave tile 32(m) x 16(n) ----
  const int m0 = (w & 1) * 32;
  const int n0 = (w >> 1) * 16;
  const unsigned short* w2p =
      w2t + ((size_t)a * NACT_ + n0 + l16) * H_ + lk * 8;
  f32x4 acc2[2];
  acc2[0] = (f32x4){0.f, 0.f, 0.f, 0.f};
  acc2[1] = (f32x4){0.f, 0.f, 0.f, 0.f};
#pragma unroll
  for (int kf = 0; kf < 16; ++kf) {
    const bf16x8 bf2 = *(const bf16x8*)(w2p + kf * 32);
#pragma unroll
    for (int mf = 0; mf < 2; ++mf) {
      const int row = m0 + mf * 16 + l16;
      const int off = row * H_ + (((kf * 4 + lk) ^ (l16 & 7))) * 8;
      const bf16x8 af2 = *(const bf16x8*)(sm.h + off);
      acc2[mf] = __builtin_amdgcn_mfma_f32_16x16x32_bf16(af2, bf2, acc2[mf],
                                                         0, 0, 0);
    }
  }
  const float b2v = bias2[a * NACT_ + n0 + l16];
  __syncthreads();
#pragma unroll
  for (int mf = 0; mf < 2; ++mf)
#pragma unroll
    for (int r = 0; r < 4; ++r)
      sm.ep.outb[m0 + mf * 16 + lk * 4 + r][n0 + l16] = acc2[mf][r] + b2v;
  __syncthreads();

  // coalesced out store: 256B contiguous per row
  {
    const int row = tid >> 3;
    const int q8 = (tid & 7) * 8;
    const f32x4 v0 = *(const f32x4*)(&sm.ep.outb[row][q8]);
    const f32x4 v1 = *(const f32x4*)(&sm.ep.outb[row][q8 + 4]);
    float* op = out + ((size_t)(b0 + row) * A_ + a) * NACT_ + q8;
    *(f32x4*)op = v0;
    *(f32x4*)(op + 4) = v1;
  }
}

extern "C" void kernel_launch(void* const* d_in, const int* in_sizes, int n_in,
                              void* d_out, int out_size, void* d_ws,
                              size_t ws_size, hipStream_t stream) {
  const float* x = (const float*)d_in[0];
  const float* w1 = (const float*)d_in[1];
  const float* b1 = (const float*)d_in[2];
  const float* w2 = (const float*)d_in[3];
  const float* b2 = (const float*)d_in[4];
  const int* routing = (const int*)d_in[5];
  float* out = (float*)d_out;

  char* ws = (char*)d_ws;
  unsigned short* w1t = (unsigned short*)(ws + WS_W1T);
  unsigned short* w2t = (unsigned short*)(ws + WS_W2T);
  float* bias1 = (float*)(ws + WS_B1);
  float* bias2 = (float*)(ws + WS_B2);

  prep_w1_n<<<A_ * 64, 256, 0, stream>>>(w1, routing, w1t);
  prep_w2<<<A_ * 8, 256, 0, stream>>>(w2, routing, w2t);
  prep_bias<<<A_, 512, 0, stream>>>(w1, b1, b2, routing, bias1, bias2);
  divtree_v7<<<A_ * 32, 512, 0, stream>>>(x, w1t, w2t, bias1, bias2, out);
}